// Round 3
// baseline (730.773 us; speedup 1.0000x reference)
//
#include <hip/hip_runtime.h>
#include <math.h>

#define NB 256
#define NT 128
#define NDW 300
#define NH 128
#define NTYPE 8
#define NLEVEL 13
#define NN (NB*NT)

#define NBK 117       // 13 node buckets + 104 edge buckets
#define CBLOCKS 64

// ib layout (ints), at byte offset 32MB of d_ws
#define BC 0                    // [CBLOCKS][NBK] per-block counts
#define BB 8192                 // [CBLOCKS][NBK] per-block base offsets
#define OFF_N 16384             // [14] node-level starts
#define OFF_E 16400             // [105] edge (level,type) starts
#define NODE_LIST 16512
#define EDGE_LIST (16512+NN)

__global__ __launch_bounds__(256) void count_kernel(const int* __restrict__ parent,
    const int* __restrict__ dep_type, const int* __restrict__ height, int* ib) {
  __shared__ int cnt[NBK];
  for (int u = threadIdx.x; u < NBK; u += 256) cnt[u] = 0;
  __syncthreads();
  for (int i = blockIdx.x*256 + threadIdx.x; i < NN; i += CBLOCKS*256) {
    atomicAdd(&cnt[height[i]], 1);
    int p = parent[i];
    if (p >= 0) {
      int gp = (i & ~(NT-1)) + p;
      atomicAdd(&cnt[13 + height[gp]*NTYPE + dep_type[i]], 1);
    }
  }
  __syncthreads();
  for (int u = threadIdx.x; u < NBK; u += 256)
    ib[BC + blockIdx.x*NBK + u] = cnt[u];
}

__global__ __launch_bounds__(128) void scan_kernel(int* ib) {
  __shared__ int total[NBK], start[NBK];
  int u = threadIdx.x;
  if (u < NBK) {
    int acc = 0;
    for (int b = 0; b < CBLOCKS; b++) {
      ib[BB + b*NBK + u] = acc;
      acc += ib[BC + b*NBK + u];
    }
    total[u] = acc;
  }
  __syncthreads();
  if (u == 0) {
    int acc = 0;
    for (int k = 0; k < 13; k++) { start[k] = acc; ib[OFF_N+k] = acc; acc += total[k]; }
    ib[OFF_N+13] = acc;
    acc = 0;
    for (int e = 0; e < 104; e++) { start[13+e] = acc; ib[OFF_E+e] = acc; acc += total[13+e]; }
    ib[OFF_E+104] = acc;
  }
  __syncthreads();
  if (u < NBK) {
    int s = start[u];
    for (int b = 0; b < CBLOCKS; b++) ib[BB + b*NBK + u] += s;
  }
}

__global__ __launch_bounds__(256) void scatter_kernel(const int* __restrict__ parent,
    const int* __restrict__ dep_type, const int* __restrict__ height, int* ib) {
  __shared__ int base[NBK];
  __shared__ int cnt[NBK];
  for (int u = threadIdx.x; u < NBK; u += 256) {
    base[u] = ib[BB + blockIdx.x*NBK + u];
    cnt[u] = 0;
  }
  __syncthreads();
  for (int i = blockIdx.x*256 + threadIdx.x; i < NN; i += CBLOCKS*256) {
    int hb = height[i];
    int pos = atomicAdd(&cnt[hb], 1);
    ib[NODE_LIST + base[hb] + pos] = i;
    int p = parent[i];
    if (p >= 0) {
      int gp = (i & ~(NT-1)) + p;
      int eb = 13 + height[gp]*NTYPE + dep_type[i];
      int pe = atomicAdd(&cnt[eb], 1);
      ib[EDGE_LIST + base[eb] + pe] = i;
    }
  }
}

// wx = token_emb @ W_wh.T  (register-tiled fp32 GEMM), also zero hbuf.
// block=128 thr (2 waves), tile 64m x 128n, thread 8m x 8n, K chunks of 20.
#define KC 20
__global__ __launch_bounds__(128) void wx_kernel(const float* __restrict__ x,
    const float* __restrict__ Wwh, float* __restrict__ wx, float* __restrict__ hbuf) {
  __shared__ __align__(16) float sxT[KC][68];    // [k][m], pitch 68
  __shared__ __align__(16) float swT[KC][132];   // [k][n], pitch 132
  int tid = threadIdx.x;
  int n0 = (tid & 15) * 8;        // 0..120
  int m0 = (tid >> 4) * 8;        // 0..56
  size_t rowbase = (size_t)blockIdx.x * 64;
  float acc[8][8];
  #pragma unroll
  for (int i = 0; i < 8; i++)
    #pragma unroll
    for (int j = 0; j < 8; j++) acc[i][j] = 0.f;
  for (int kc = 0; kc < NDW; kc += KC) {
    __syncthreads();
    // stage x chunk transposed: 64 rows x 5 float4
    for (int idx = tid; idx < 64*5; idx += 128) {
      int r = idx / 5, q = idx % 5;
      float4 v = *(const float4*)&x[(rowbase + r)*NDW + kc + q*4];
      sxT[q*4+0][r] = v.x; sxT[q*4+1][r] = v.y; sxT[q*4+2][r] = v.z; sxT[q*4+3][r] = v.w;
    }
    // stage W chunk transposed: 128 rows x 5 float4
    for (int idx = tid; idx < 128*5; idx += 128) {
      int r = idx / 5, q = idx % 5;
      float4 v = *(const float4*)&Wwh[(size_t)r*NDW + kc + q*4];
      swT[q*4+0][r] = v.x; swT[q*4+1][r] = v.y; swT[q*4+2][r] = v.z; swT[q*4+3][r] = v.w;
    }
    __syncthreads();
    #pragma unroll 5
    for (int kk = 0; kk < KC; kk++) {
      float4 a0 = *(const float4*)&sxT[kk][m0];
      float4 a1 = *(const float4*)&sxT[kk][m0+4];
      float4 b0 = *(const float4*)&swT[kk][n0];
      float4 b1 = *(const float4*)&swT[kk][n0+4];
      float am[8] = {a0.x,a0.y,a0.z,a0.w,a1.x,a1.y,a1.z,a1.w};
      float bn[8] = {b0.x,b0.y,b0.z,b0.w,b1.x,b1.y,b1.z,b1.w};
      #pragma unroll
      for (int i = 0; i < 8; i++)
        #pragma unroll
        for (int j = 0; j < 8; j++) acc[i][j] += am[i]*bn[j];
    }
  }
  #pragma unroll
  for (int i = 0; i < 8; i++) {
    *(float4*)&wx[(rowbase+m0+i)*NH + n0]     = *(float4*)&acc[i][0];
    *(float4*)&wx[(rowbase+m0+i)*NH + n0 + 4] = *(float4*)&acc[i][4];
  }
  // zero hbuf for these 64 rows
  float4 z = make_float4(0.f,0.f,0.f,0.f);
  for (int idx = tid; idx < 64*32; idx += 128) {
    int r = idx >> 5, q = idx & 31;
    *(float4*)&hbuf[(rowbase+r)*NH + q*4] = z;
  }
}

// per level k: finalize h for nodes at height k, then g = W_hr @ h.
// One wave processes 8 nodes per pass: weight float4s reused 8x.
__global__ __launch_bounds__(256) void node_kernel(const float* __restrict__ Whr,
    const float* __restrict__ wx, const float* __restrict__ bwh,
    const int* __restrict__ ib, float* __restrict__ hbuf, float* __restrict__ g, int k) {
  int start = ib[OFF_N+k], end = ib[OFF_N+k+1];
  int ngrp = (end - start + 7) >> 3;
  if ((int)blockIdx.x*4 >= ngrp) return;          // uniform early-exit before staging
  __shared__ __align__(16) float sW[NH*132];
  __shared__ __align__(16) float sh[4][8][NH];
  for (int idx = threadIdx.x; idx < NH*NH; idx += 256)
    sW[(idx>>7)*132 + (idx&127)] = Whr[idx];
  __syncthreads();
  int wave = threadIdx.x >> 6, lane = threadIdx.x & 63;
  float b0 = bwh[lane], b1 = bwh[64+lane];
  for (int grp = (int)blockIdx.x*4 + wave; grp < ngrp; grp += gridDim.x*4) {
    int base = start + grp*8;
    int cnt = end - base; if (cnt > 8) cnt = 8;
    int idxs[8];
    #pragma unroll
    for (int j = 0; j < 8; j++) {
      if (j < cnt) {
        int i = ib[NODE_LIST + base + j];
        idxs[j] = i;
        float s0 = tanhf(wx[(size_t)i*NH + lane]      + b0);
        float s1 = tanhf(wx[(size_t)i*NH + 64 + lane] + b1);
        float h0, h1;
        if (k == 0) { h0 = s0; h1 = s1; }
        else {
          h0 = tanhf(hbuf[(size_t)i*NH + lane]      + s0);
          h1 = tanhf(hbuf[(size_t)i*NH + 64 + lane] + s1);
        }
        hbuf[(size_t)i*NH + lane]      = h0;
        hbuf[(size_t)i*NH + 64 + lane] = h1;
        sh[wave][j][lane] = h0; sh[wave][j][64+lane] = h1;  // wave-synchronous LDS
      } else {
        sh[wave][j][lane] = 0.f; sh[wave][j][64+lane] = 0.f;
      }
    }
    float g0[8], g1[8];
    #pragma unroll
    for (int j = 0; j < 8; j++) { g0[j] = 0.f; g1[j] = 0.f; }
    #pragma unroll 8
    for (int d4 = 0; d4 < 32; d4++) {
      float4 w0 = *(const float4*)&sW[lane*132 + d4*4];
      float4 w1 = *(const float4*)&sW[(lane+64)*132 + d4*4];
      #pragma unroll
      for (int j = 0; j < 8; j++) {
        float4 hv = *(const float4*)&sh[wave][j][d4*4];
        g0[j] += w0.x*hv.x + w0.y*hv.y + w0.z*hv.z + w0.w*hv.w;
        g1[j] += w1.x*hv.x + w1.y*hv.y + w1.z*hv.z + w1.w*hv.w;
      }
    }
    for (int j = 0; j < cnt; j++) {
      g[(size_t)idxs[j]*NH + lane]      = g0[j];
      g[(size_t)idxs[j]*NH + 64 + lane] = g1[j];
    }
  }
}

// per level k, edges bucketed by type t = blockIdx&7:
// infl = W_rel[t] @ tanh(g_child + wx_parent); accumulate into hbuf[parent].
// One wave processes 8 edges per pass.
__global__ __launch_bounds__(256) void edge_kernel(const float* __restrict__ Wrel,
    const float* __restrict__ wx, const float* __restrict__ g,
    const int* __restrict__ parent, const int* __restrict__ ib,
    float* __restrict__ hbuf, int k) {
  int t = blockIdx.x & 7;
  int cb = blockIdx.x >> 3;
  int bstart = ib[OFF_E + k*NTYPE + t];
  int bend   = ib[OFF_E + k*NTYPE + t + 1];
  int ngrp = (bend - bstart + 7) >> 3;
  if (cb*4 >= ngrp) return;                       // uniform early-exit before staging
  __shared__ __align__(16) float sW[NH*132];
  __shared__ __align__(16) float sr[4][8][NH];
  for (int idx = threadIdx.x; idx < NH*NH; idx += 256)
    sW[(idx>>7)*132 + (idx&127)] = Wrel[(size_t)t*NH*NH + idx];
  __syncthreads();
  int wave = threadIdx.x >> 6, lane = threadIdx.x & 63;
  int EB = gridDim.x >> 3;
  for (int grp = cb*4 + wave; grp < ngrp; grp += EB*4) {
    int base = bstart + grp*8;
    int cnt = bend - base; if (cnt > 8) cnt = 8;
    int pidx[8];
    #pragma unroll
    for (int j = 0; j < 8; j++) {
      if (j < cnt) {
        int c = ib[EDGE_LIST + base + j];
        int p = (c & ~(NT-1)) + parent[c];
        pidx[j] = p;
        float r0 = tanhf(g[(size_t)c*NH + lane]      + wx[(size_t)p*NH + lane]);
        float r1 = tanhf(g[(size_t)c*NH + 64 + lane] + wx[(size_t)p*NH + 64 + lane]);
        sr[wave][j][lane] = r0; sr[wave][j][64+lane] = r1;  // wave-synchronous LDS
      } else {
        sr[wave][j][lane] = 0.f; sr[wave][j][64+lane] = 0.f;
      }
    }
    float i0[8], i1[8];
    #pragma unroll
    for (int j = 0; j < 8; j++) { i0[j] = 0.f; i1[j] = 0.f; }
    #pragma unroll 8
    for (int d4 = 0; d4 < 32; d4++) {
      float4 w0 = *(const float4*)&sW[lane*132 + d4*4];
      float4 w1 = *(const float4*)&sW[(lane+64)*132 + d4*4];
      #pragma unroll
      for (int j = 0; j < 8; j++) {
        float4 rv = *(const float4*)&sr[wave][j][d4*4];
        i0[j] += w0.x*rv.x + w0.y*rv.y + w0.z*rv.z + w0.w*rv.w;
        i1[j] += w1.x*rv.x + w1.y*rv.y + w1.z*rv.z + w1.w*rv.w;
      }
    }
    for (int j = 0; j < cnt; j++) {
      atomicAdd(&hbuf[(size_t)pidx[j]*NH + lane],      i0[j]);
      atomicAdd(&hbuf[(size_t)pidx[j]*NH + 64 + lane], i1[j]);
    }
  }
}

extern "C" void kernel_launch(void* const* d_in, const int* in_sizes, int n_in,
                              void* d_out, int out_size, void* d_ws, size_t ws_size,
                              hipStream_t stream) {
  const float* token  = (const float*)d_in[0];
  const float* Wwh    = (const float*)d_in[1];
  const float* bwh    = (const float*)d_in[2];
  const float* Whr    = (const float*)d_in[3];
  const float* Wrel   = (const float*)d_in[4];
  const int*   parent = (const int*)d_in[5];
  const int*   dep    = (const int*)d_in[6];
  const int*   height = (const int*)d_in[7];

  float* hbuf = (float*)d_out;                          // seg-accumulator, then final h
  float* wx   = (float*)d_ws;                           // [NN,NH] f32, 16MB
  float* g    = (float*)((char*)d_ws + 16777216);       // [NN,NH] f32, 16MB
  int*   ib   = (int*)((char*)d_ws + 33554432);         // bucket metadata + lists

  count_kernel<<<CBLOCKS, 256, 0, stream>>>(parent, dep, height, ib);
  scan_kernel<<<1, 128, 0, stream>>>(ib);
  scatter_kernel<<<CBLOCKS, 256, 0, stream>>>(parent, dep, height, ib);
  wx_kernel<<<NN/64, 128, 0, stream>>>(token, Wwh, wx, hbuf);
  node_kernel<<<256, 256, 0, stream>>>(Whr, wx, bwh, ib, hbuf, g, 0);
  for (int k = 1; k < NLEVEL; k++) {
    edge_kernel<<<NTYPE*64, 256, 0, stream>>>(Wrel, wx, g, parent, ib, hbuf, k);
    node_kernel<<<256, 256, 0, stream>>>(Whr, wx, bwh, ib, hbuf, g, k);
  }
}